// Round 1
// baseline (197.032 us; speedup 1.0000x reference)
//
#include <hip/hip_runtime.h>

// Sliding-window causal self-attention, B=4, S=4096, d=64, window [i-256, i].
// Flash-style online softmax. One block per (batch, 64-query tile): grid 256
// blocks = 1 block/CU. fp32 VALU baseline (no fp32 MFMA exists on CDNA4).

#define SLOG2E 1.4426950408889634f

__global__ __launch_bounds__(256) void swa_kernel(const float* __restrict__ qkv,
                                                  float* __restrict__ out)
{
    const int b  = blockIdx.y;
    const int q0 = blockIdx.x * 64;
    const int t  = threadIdx.x;
    const int tq4 = t >> 4;   // 0..15: query group (4 queries each)
    const int tk4 = t & 15;   // 0..15: key group / out-dim group (4 each)

    // XOR-swizzled float4 tiles: element [r][c4] stored at c4 ^ ((r>>2)&15).
    // All compute-phase b128 patterns land at <=2-way bank aliasing (free).
    __shared__ float4 Qs4[64 * 16];
    __shared__ float4 Ks4[64 * 16];
    __shared__ float4 Vs4[64 * 16];
    __shared__ float4 Ps4[64 * 16];   // exact 64 KB total

    const float4* qkv4 = (const float4*)qkv;   // 48 float4 per (b,s) row

    // ---- stage Q tile (scaled later at score stage) ----
    {
        const size_t base = (size_t)(b * 4096 + q0) * 48;
        #pragma unroll
        for (int s = 0; s < 4; ++s) {
            int r = (t >> 4) + 16 * s;
            int c4 = t & 15;
            Qs4[r * 16 + (c4 ^ ((r >> 2) & 15))] = qkv4[base + (size_t)r * 48 + c4];
        }
    }

    float m[4], l[4], acc[4][4];
    #pragma unroll
    for (int i = 0; i < 4; ++i) {
        m[i] = -1e30f; l[i] = 0.f;
        #pragma unroll
        for (int j = 0; j < 4; ++j) acc[i][j] = 0.f;
    }

    for (int c = 0; c < 5; ++c) {
        const int kb = q0 - 256 + 64 * c;       // key-chunk start (uniform)
        if (kb < 0) continue;                    // whole chunk out of range

        __syncthreads();   // A: prev-iter PV readers done before restaging
        {
            const size_t base = (size_t)(b * 4096 + kb) * 48;
            #pragma unroll
            for (int s = 0; s < 4; ++s) {
                int r = (t >> 4) + 16 * s;
                int c4 = t & 15;
                int sw = r * 16 + (c4 ^ ((r >> 2) & 15));
                Ks4[sw] = qkv4[base + (size_t)r * 48 + 16 + c4];
                Vs4[sw] = qkv4[base + (size_t)r * 48 + 32 + c4];
            }
        }
        __syncthreads();   // B: tiles visible

        // ---- S = Q K^T (64x64), 4x4 register tile per thread ----
        float sc[4][4];
        #pragma unroll
        for (int i = 0; i < 4; ++i)
            #pragma unroll
            for (int j = 0; j < 4; ++j) sc[i][j] = 0.f;

        #pragma unroll
        for (int d4 = 0; d4 < 16; ++d4) {
            float4 qv[4], kv[4];
            #pragma unroll
            for (int i = 0; i < 4; ++i) qv[i] = Qs4[(4 * tq4 + i) * 16 + (d4 ^ tq4)];
            #pragma unroll
            for (int j = 0; j < 4; ++j) kv[j] = Ks4[(4 * tk4 + j) * 16 + (d4 ^ tk4)];
            #pragma unroll
            for (int i = 0; i < 4; ++i)
                #pragma unroll
                for (int j = 0; j < 4; ++j)
                    sc[i][j] += qv[i].x * kv[j].x + qv[i].y * kv[j].y
                              + qv[i].z * kv[j].z + qv[i].w * kv[j].w;
        }

        // ---- scale + sliding-window mask: valid iff 0 <= (i-j) <= 256 ----
        const int base_d = 256 - 64 * c + 4 * tq4 - 4 * tk4;
        #pragma unroll
        for (int i = 0; i < 4; ++i)
            #pragma unroll
            for (int j = 0; j < 4; ++j) {
                int delta = base_d + i - j;
                sc[i][j] = ((unsigned)delta <= 256u) ? sc[i][j] * 0.125f : -1e30f;
            }

        // ---- online softmax (row = query lives across a 16-lane group) ----
        float p[4][4];
        #pragma unroll
        for (int i = 0; i < 4; ++i) {
            float mx = fmaxf(fmaxf(sc[i][0], sc[i][1]), fmaxf(sc[i][2], sc[i][3]));
            #pragma unroll
            for (int off = 1; off < 16; off <<= 1) mx = fmaxf(mx, __shfl_xor(mx, off));
            float mnew  = fmaxf(m[i], mx);
            float alpha = __builtin_amdgcn_exp2f((m[i] - mnew) * SLOG2E);
            m[i] = mnew;
            float rs = 0.f;
            #pragma unroll
            for (int j = 0; j < 4; ++j) {
                float pp = __builtin_amdgcn_exp2f((sc[i][j] - mnew) * SLOG2E);
                p[i][j] = pp; rs += pp;
            }
            #pragma unroll
            for (int off = 1; off < 16; off <<= 1) rs += __shfl_xor(rs, off);
            l[i] = l[i] * alpha + rs;
            #pragma unroll
            for (int j = 0; j < 4; ++j) acc[i][j] *= alpha;
        }

        // ---- P to LDS for the PV pass (needs cross-thread columns) ----
        #pragma unroll
        for (int i = 0; i < 4; ++i)
            Ps4[(4 * tq4 + i) * 16 + (tk4 ^ tq4)] =
                make_float4(p[i][0], p[i][1], p[i][2], p[i][3]);
        __syncthreads();   // C: P visible

        // ---- O += P V : queries 4*tq4+i, out-dims 4*tk4+j ----
        #pragma unroll
        for (int k4 = 0; k4 < 16; ++k4) {
            float4 pv[4], vv[4];
            #pragma unroll
            for (int i = 0; i < 4; ++i)  pv[i]  = Ps4[(4 * tq4 + i) * 16 + (k4 ^ tq4)];
            #pragma unroll
            for (int kk = 0; kk < 4; ++kk) vv[kk] = Vs4[(4 * k4 + kk) * 16 + (tk4 ^ k4)];
            #pragma unroll
            for (int i = 0; i < 4; ++i) {
                acc[i][0] += pv[i].x * vv[0].x + pv[i].y * vv[1].x + pv[i].z * vv[2].x + pv[i].w * vv[3].x;
                acc[i][1] += pv[i].x * vv[0].y + pv[i].y * vv[1].y + pv[i].z * vv[2].y + pv[i].w * vv[3].y;
                acc[i][2] += pv[i].x * vv[0].z + pv[i].y * vv[1].z + pv[i].z * vv[2].z + pv[i].w * vv[3].z;
                acc[i][3] += pv[i].x * vv[0].w + pv[i].y * vv[1].w + pv[i].z * vv[2].w + pv[i].w * vv[3].w;
            }
        }
    }

    // ---- epilogue: normalize and store (coalesced float4) ----
    float4* out4 = (float4*)out;
    const size_t obase = (size_t)(b * 4096 + q0) * 16;
    #pragma unroll
    for (int i = 0; i < 4; ++i) {
        float inv = 1.0f / l[i];
        out4[obase + (size_t)(4 * tq4 + i) * 16 + tk4] =
            make_float4(acc[i][0] * inv, acc[i][1] * inv, acc[i][2] * inv, acc[i][3] * inv);
    }
}

extern "C" void kernel_launch(void* const* d_in, const int* in_sizes, int n_in,
                              void* d_out, int out_size, void* d_ws, size_t ws_size,
                              hipStream_t stream) {
    const float* qkv = (const float*)d_in[0];
    float* out = (float*)d_out;
    dim3 grid(64, 4);       // 256 blocks = 1 per CU
    dim3 block(256);
    hipLaunchKernelGGL(swa_kernel, grid, block, 0, stream, qkv, out);
}

// Round 2
// 69.713 us; speedup vs baseline: 2.8263x; 2.8263x over previous
//
#include <hip/hip_runtime.h>
#include <hip/hip_bf16.h>

// Sliding-window causal attention, B=4, S=4096, d=64, window [i-256, i].
// bf16 MFMA flash kernel: one block per (batch, 64-query tile), 4 waves,
// each wave owns a 16-query stripe. 64-key chunks, online softmax.
// mfma_f32_16x16x32_bf16; A-layout A[m=lane&15][k=quad*8+j],
// C/D col=lane&15,row=quad*4+reg (HW-verified mappings per guide §3).

#define LOG2E 1.4426950408889634f

typedef __attribute__((ext_vector_type(8))) short  frag;    // 8 bf16 = 4 VGPRs
typedef __attribute__((ext_vector_type(4))) float  f32x4;   // C/D

static __device__ inline short f2bf(float x) {
    __hip_bfloat16 h = __float2bfloat16(x);   // RTNE
    return __builtin_bit_cast(short, h);
}

#define LSTR 72   // LDS row stride in bf16 (144 B): breaks pow-2 bank aliasing

__global__ __launch_bounds__(256) void swa_mfma(const float* __restrict__ qkv,
                                                float* __restrict__ out)
{
    __shared__ short Qs[64 * LSTR];
    __shared__ short Ks[64 * LSTR];
    __shared__ short Vt[64 * LSTR];     // transposed: Vt[d][key]
    __shared__ short Pw[4][16 * LSTR];  // per-wave P tile  (total ~36 KB)

    const int b    = blockIdx.y;
    const int q0   = blockIdx.x * 64;
    const int t    = threadIdx.x;
    const int w    = t >> 6;      // wave 0..3 -> query stripe 16w..16w+15
    const int lane = t & 63;
    const int cl   = lane & 15;   // "column" lane id
    const int quad = lane >> 4;   // 0..3

    const float4* qkv4 = (const float4*)qkv;   // 48 float4 per (b,s) row
    const int r_st  = t >> 2;     // staging row 0..63
    const int c4_st = t & 3;      // staging float4-col base

    // ---- stage Q (scale 1/8 folded in; pow-2 => exact) ----
    {
        const size_t base = (size_t)(b * 4096 + q0 + r_st) * 48;
        #pragma unroll
        for (int i = 0; i < 4; ++i) {
            float4 v = qkv4[base + c4_st + 4 * i];
            short4 s4 = { f2bf(v.x * 0.125f), f2bf(v.y * 0.125f),
                          f2bf(v.z * 0.125f), f2bf(v.w * 0.125f) };
            *(short4*)&Qs[r_st * LSTR + 4 * (c4_st + 4 * i)] = s4;
        }
    }

    // first valid chunk: key-chunk start kb = q0-256+64c >= 0
    const int c0 = (q0 >= 256) ? 0 : (4 - (q0 >> 6));

    // ---- prefetch chunk c0 K/V (fp32, in flight across barrier) ----
    float4 preK[4], preV[4];
    {
        const int kb = q0 - 256 + 64 * c0;
        const size_t base = (size_t)(b * 4096 + kb + r_st) * 48;
        #pragma unroll
        for (int i = 0; i < 4; ++i) {
            preK[i] = qkv4[base + 16 + c4_st + 4 * i];
            preV[i] = qkv4[base + 32 + c4_st + 4 * i];
        }
    }

    __syncthreads();   // Qs visible
    // Q A-fragments, reused across all chunks (row = 16w + cl)
    const frag qf0 = *(const frag*)&Qs[(16 * w + cl) * LSTR + 8 * quad];
    const frag qf1 = *(const frag*)&Qs[(16 * w + cl) * LSTR + 32 + 8 * quad];

    float m[4], l[4];
    f32x4 oacc[4];
    #pragma unroll
    for (int r = 0; r < 4; ++r) { m[r] = -1e30f; l[r] = 0.f; }
    #pragma unroll
    for (int t4 = 0; t4 < 4; ++t4) oacc[t4] = (f32x4){0.f, 0.f, 0.f, 0.f};

    const int ql = 4 * quad;   // + r = query row within the 16-stripe (C/D row)

    for (int c = c0; c < 5; ++c) {
        __syncthreads();   // A: previous chunk's K/V readers done

        // ---- cvt + write K, V(transposed) to LDS ----
        #pragma unroll
        for (int i = 0; i < 4; ++i) {
            short4 k4 = { f2bf(preK[i].x), f2bf(preK[i].y),
                          f2bf(preK[i].z), f2bf(preK[i].w) };
            *(short4*)&Ks[r_st * LSTR + 4 * (c4_st + 4 * i)] = k4;
            const int d0 = 4 * (c4_st + 4 * i);
            Vt[(d0 + 0) * LSTR + r_st] = f2bf(preV[i].x);
            Vt[(d0 + 1) * LSTR + r_st] = f2bf(preV[i].y);
            Vt[(d0 + 2) * LSTR + r_st] = f2bf(preV[i].z);
            Vt[(d0 + 3) * LSTR + r_st] = f2bf(preV[i].w);
        }
        __syncthreads();   // B: tiles visible

        // ---- issue next chunk's global loads (overlap with compute) ----
        if (c < 4) {
            const int kb = q0 - 256 + 64 * (c + 1);
            const size_t base = (size_t)(b * 4096 + kb + r_st) * 48;
            #pragma unroll
            for (int i = 0; i < 4; ++i) {
                preK[i] = qkv4[base + 16 + c4_st + 4 * i];
                preV[i] = qkv4[base + 32 + c4_st + 4 * i];
            }
        }

        // ---- S = Q K^T : 4 key-tiles of 16x16, K-dim 64 = 2 MFMA steps ----
        f32x4 sc[4];
        #pragma unroll
        for (int t4 = 0; t4 < 4; ++t4) sc[t4] = (f32x4){0.f, 0.f, 0.f, 0.f};
        #pragma unroll
        for (int t4 = 0; t4 < 4; ++t4) {
            const frag kf0 = *(const frag*)&Ks[(16 * t4 + cl) * LSTR + 8 * quad];
            const frag kf1 = *(const frag*)&Ks[(16 * t4 + cl) * LSTR + 32 + 8 * quad];
            sc[t4] = __builtin_amdgcn_mfma_f32_16x16x32_bf16(qf0, kf0, sc[t4], 0, 0, 0);
            sc[t4] = __builtin_amdgcn_mfma_f32_16x16x32_bf16(qf1, kf1, sc[t4], 0, 0, 0);
        }

        // ---- sliding-window mask (only edge chunks need it) ----
        // i-j = q_local - k_local + 256 - 64c; c==4: need q>=k; c==0: need q<=k
        if (c == 4) {
            #pragma unroll
            for (int t4 = 0; t4 < 4; ++t4)
                #pragma unroll
                for (int r = 0; r < 4; ++r)
                    if (16 * w + ql + r < 16 * t4 + cl) sc[t4][r] = -1e30f;
        } else if (c == 0) {
            #pragma unroll
            for (int t4 = 0; t4 < 4; ++t4)
                #pragma unroll
                for (int r = 0; r < 4; ++r)
                    if (16 * w + ql + r > 16 * t4 + cl) sc[t4][r] = -1e30f;
        }

        // ---- online softmax (row = lanes of same quad group; 16-lane shfl) ----
        #pragma unroll
        for (int r = 0; r < 4; ++r) {
            float mx = fmaxf(fmaxf(sc[0][r], sc[1][r]), fmaxf(sc[2][r], sc[3][r]));
            #pragma unroll
            for (int off = 1; off < 16; off <<= 1) mx = fmaxf(mx, __shfl_xor(mx, off));
            const float mnew  = fmaxf(m[r], mx);
            const float alpha = __builtin_amdgcn_exp2f((m[r] - mnew) * LOG2E);
            m[r] = mnew;
            float sum = 0.f;
            #pragma unroll
            for (int t4 = 0; t4 < 4; ++t4) {
                float p = __builtin_amdgcn_exp2f((sc[t4][r] - mnew) * LOG2E);
                Pw[w][(ql + r) * LSTR + 16 * t4 + cl] = f2bf(p);
                sum += p;
            }
            #pragma unroll
            for (int off = 1; off < 16; off <<= 1) sum += __shfl_xor(sum, off);
            l[r] = l[r] * alpha + sum;
            #pragma unroll
            for (int t4 = 0; t4 < 4; ++t4) oacc[t4][r] *= alpha;
        }

        // ---- O += P V  (P per-wave private: no barrier, lgkmcnt only) ----
        const frag pf0 = *(const frag*)&Pw[w][cl * LSTR + 8 * quad];
        const frag pf1 = *(const frag*)&Pw[w][cl * LSTR + 32 + 8 * quad];
        #pragma unroll
        for (int t4 = 0; t4 < 4; ++t4) {
            const frag vf0 = *(const frag*)&Vt[(16 * t4 + cl) * LSTR + 8 * quad];
            const frag vf1 = *(const frag*)&Vt[(16 * t4 + cl) * LSTR + 32 + 8 * quad];
            oacc[t4] = __builtin_amdgcn_mfma_f32_16x16x32_bf16(pf0, vf0, oacc[t4], 0, 0, 0);
            oacc[t4] = __builtin_amdgcn_mfma_f32_16x16x32_bf16(pf1, vf1, oacc[t4], 0, 0, 0);
        }
    }

    // ---- epilogue: normalize, store (16-lane groups hit 64B segments) ----
    #pragma unroll
    for (int r = 0; r < 4; ++r) {
        const float inv = 1.0f / l[r];
        const size_t row = (size_t)(b * 4096 + q0 + 16 * w + ql + r) * 64;
        #pragma unroll
        for (int t4 = 0; t4 < 4; ++t4)
            out[row + 16 * t4 + cl] = oacc[t4][r] * inv;
    }
}

extern "C" void kernel_launch(void* const* d_in, const int* in_sizes, int n_in,
                              void* d_out, int out_size, void* d_ws, size_t ws_size,
                              hipStream_t stream) {
    const float* qkv = (const float*)d_in[0];
    float* out = (float*)d_out;
    dim3 grid(64, 4);    // 256 blocks = 1 per CU
    dim3 block(256);
    hipLaunchKernelGGL(swa_mfma, grid, block, 0, stream, qkv, out);
}

// Round 3
// 67.600 us; speedup vs baseline: 2.9147x; 1.0313x over previous
//
#include <hip/hip_runtime.h>
#include <hip/hip_bf16.h>

// Sliding-window causal attention, B=4, S=4096, d=64, window [i-256, i].
// bf16 MFMA flash kernel, round 3:
//  - 512-thread blocks (8 waves): 4 query-stripes x 2 key-groups (key-split
//    flash with end merge) -> 2048 waves = 2 waves/SIMD latency hiding.
//  - DPP-based 16-lane softmax reductions (no DS-latency shuffle chains).
// Layouts (HW-verified per guide §3): A[m=lane&15][k=quad*8+j];
// C/D col=lane&15, row=quad*4+reg.

#define LOG2E 1.4426950408889634f

typedef __attribute__((ext_vector_type(8))) short  frag;    // 8 bf16
typedef __attribute__((ext_vector_type(4))) float  f32x4;   // C/D

static __device__ inline short f2bf(float x) {
    __hip_bfloat16 h = __float2bfloat16(x);   // RTNE
    return __builtin_bit_cast(short, h);
}

// DPP cross-lane within a 16-lane row: xor1, xor2, then half-mirror (==xor4
// once quad-uniform) and mirror (==xor8 once 8-uniform).
#define DPPF(x, ctrl) __builtin_bit_cast(float, \
    __builtin_amdgcn_mov_dpp(__builtin_bit_cast(int, (x)), (ctrl), 0xF, 0xF, true))

static __device__ inline float red16_max(float x) {
    x = fmaxf(x, DPPF(x, 0xB1));   // quad_perm [1,0,3,2]  (xor 1)
    x = fmaxf(x, DPPF(x, 0x4E));   // quad_perm [2,3,0,1]  (xor 2)
    x = fmaxf(x, DPPF(x, 0x141));  // row_half_mirror      (xor 7 ~ xor 4)
    x = fmaxf(x, DPPF(x, 0x140));  // row_mirror           (xor 15 ~ xor 8)
    return x;
}
static __device__ inline float red16_sum(float x) {
    x += DPPF(x, 0xB1);
    x += DPPF(x, 0x4E);
    x += DPPF(x, 0x141);
    x += DPPF(x, 0x140);
    return x;
}

#define LSTR 72   // K/V/Q LDS row stride (bf16)
#define PSTR 40   // P tile row stride (16 x 32 keys + pad)
#define OSTR 65   // merge buffer row stride (fp32)

__global__ __launch_bounds__(512, 2) void swa_mfma2(const float* __restrict__ qkv,
                                                    float* __restrict__ out)
{
    __shared__ short Qs[64 * LSTR];
    __shared__ short Ks[64 * LSTR];
    __shared__ short Vt[64 * LSTR];       // Vt[dim][key]
    __shared__ short Pw[8][16 * PSTR];    // per-wave P (16 q x 32 keys)
    __shared__ float Om[4][16 * OSTR];    // group-1 O partials per stripe
    __shared__ float2 mlbuf[4][16];       // group-1 (m,l) per stripe row

    const int b    = blockIdx.y;
    const int q0   = blockIdx.x * 64;
    const int t    = threadIdx.x;
    const int w    = t >> 6;        // 0..7
    const int s    = w & 3;         // query stripe: rows 16s..16s+15
    const int g    = w >> 2;        // key group: tiles {2g, 2g+1}
    const int lane = t & 63;
    const int cl   = lane & 15;
    const int quad = lane >> 4;
    const int ql   = 4 * quad;

    const float4* qkv4 = (const float4*)qkv;   // 48 float4 per (b,seq) row
    const int r_st = t >> 3;        // staging row 0..63
    const int c8   = t & 7;         // staging float4-col (two: c8, c8+8)

    // ---- stage Q (x 1/8 exact) ----
    {
        const size_t base = (size_t)(b * 4096 + q0 + r_st) * 48;
        #pragma unroll
        for (int i = 0; i < 2; ++i) {
            float4 v = qkv4[base + c8 + 8 * i];
            short4 s4 = { f2bf(v.x * 0.125f), f2bf(v.y * 0.125f),
                          f2bf(v.z * 0.125f), f2bf(v.w * 0.125f) };
            *(short4*)&Qs[r_st * LSTR + 4 * (c8 + 8 * i)] = s4;
        }
    }

    const int c0 = (q0 >= 256) ? 0 : (4 - (q0 >> 6));

    // ---- prefetch chunk c0 ----
    float4 preK[2], preV[2];
    {
        const int kb = q0 - 256 + 64 * c0;
        const size_t base = (size_t)(b * 4096 + kb + r_st) * 48;
        #pragma unroll
        for (int i = 0; i < 2; ++i) {
            preK[i] = qkv4[base + 16 + c8 + 8 * i];
            preV[i] = qkv4[base + 32 + c8 + 8 * i];
        }
    }

    __syncthreads();   // Qs visible
    const frag qf0 = *(const frag*)&Qs[(16 * s + cl) * LSTR + 8 * quad];
    const frag qf1 = *(const frag*)&Qs[(16 * s + cl) * LSTR + 32 + 8 * quad];

    float m[4], l[4];
    f32x4 oacc[4];
    #pragma unroll
    for (int r = 0; r < 4; ++r) { m[r] = -1e30f; l[r] = 0.f; }
    #pragma unroll
    for (int n4 = 0; n4 < 4; ++n4) oacc[n4] = (f32x4){0.f, 0.f, 0.f, 0.f};

    for (int c = c0; c < 5; ++c) {
        __syncthreads();   // A: prev chunk's readers done

        // ---- cvt + store K (row-major) and V (transposed) ----
        #pragma unroll
        for (int i = 0; i < 2; ++i) {
            short4 k4 = { f2bf(preK[i].x), f2bf(preK[i].y),
                          f2bf(preK[i].z), f2bf(preK[i].w) };
            *(short4*)&Ks[r_st * LSTR + 4 * (c8 + 8 * i)] = k4;
            const int d0 = 4 * (c8 + 8 * i);
            Vt[(d0 + 0) * LSTR + r_st] = f2bf(preV[i].x);
            Vt[(d0 + 1) * LSTR + r_st] = f2bf(preV[i].y);
            Vt[(d0 + 2) * LSTR + r_st] = f2bf(preV[i].z);
            Vt[(d0 + 3) * LSTR + r_st] = f2bf(preV[i].w);
        }
        __syncthreads();   // B: tiles visible

        // ---- prefetch next chunk (lands during compute) ----
        if (c < 4) {
            const int kb = q0 - 256 + 64 * (c + 1);
            const size_t base = (size_t)(b * 4096 + kb + r_st) * 48;
            #pragma unroll
            for (int i = 0; i < 2; ++i) {
                preK[i] = qkv4[base + 16 + c8 + 8 * i];
                preV[i] = qkv4[base + 32 + c8 + 8 * i];
            }
        }

        // ---- S = Q K^T over this group's 2 key-tiles ----
        f32x4 sc[2];
        #pragma unroll
        for (int u = 0; u < 2; ++u) {
            const int t4 = 2 * g + u;
            sc[u] = (f32x4){0.f, 0.f, 0.f, 0.f};
            const frag kf0 = *(const frag*)&Ks[(16 * t4 + cl) * LSTR + 8 * quad];
            const frag kf1 = *(const frag*)&Ks[(16 * t4 + cl) * LSTR + 32 + 8 * quad];
            sc[u] = __builtin_amdgcn_mfma_f32_16x16x32_bf16(qf0, kf0, sc[u], 0, 0, 0);
            sc[u] = __builtin_amdgcn_mfma_f32_16x16x32_bf16(qf1, kf1, sc[u], 0, 0, 0);
        }

        // ---- sliding-window mask (edge chunks only) ----
        if (c == 4) {           // causal: keep key <= query
            #pragma unroll
            for (int u = 0; u < 2; ++u) {
                const int t4 = 2 * g + u;
                #pragma unroll
                for (int r = 0; r < 4; ++r)
                    if (16 * s + ql + r < 16 * t4 + cl) sc[u][r] = -1e30f;
            }
        } else if (c == 0) {    // left edge: keep key >= query
            #pragma unroll
            for (int u = 0; u < 2; ++u) {
                const int t4 = 2 * g + u;
                #pragma unroll
                for (int r = 0; r < 4; ++r)
                    if (16 * s + ql + r > 16 * t4 + cl) sc[u][r] = -1e30f;
            }
        }

        // ---- online softmax (DPP 16-lane reductions) ----
        #pragma unroll
        for (int r = 0; r < 4; ++r) {
            float mx = red16_max(fmaxf(sc[0][r], sc[1][r]));
            const float mnew  = fmaxf(m[r], mx);
            const float alpha = __builtin_amdgcn_exp2f((m[r] - mnew) * LOG2E);
            m[r] = mnew;
            float sum = 0.f;
            #pragma unroll
            for (int u = 0; u < 2; ++u) {
                // guard: fully-masked tile would give exp(-1e30 - -1e30)=1
                float p = (sc[u][r] <= -1e29f)
                            ? 0.f
                            : __builtin_amdgcn_exp2f((sc[u][r] - mnew) * LOG2E);
                Pw[w][(ql + r) * PSTR + 16 * u + cl] = f2bf(p);
                sum += p;
            }
            l[r] = l[r] * alpha + red16_sum(sum);
            #pragma unroll
            for (int n4 = 0; n4 < 4; ++n4) oacc[n4][r] *= alpha;
        }

        // ---- O += P V  (P wave-private: lgkmcnt only, no barrier) ----
        const frag pf = *(const frag*)&Pw[w][cl * PSTR + 8 * quad];
        #pragma unroll
        for (int n4 = 0; n4 < 4; ++n4) {
            const frag vf = *(const frag*)&Vt[(16 * n4 + cl) * LSTR + 32 * g + 8 * quad];
            oacc[n4] = __builtin_amdgcn_mfma_f32_16x16x32_bf16(pf, vf, oacc[n4], 0, 0, 0);
        }
    }

    // ---- merge the two key-groups per stripe ----
    if (g == 1) {
        #pragma unroll
        for (int n4 = 0; n4 < 4; ++n4)
            #pragma unroll
            for (int r = 0; r < 4; ++r)
                Om[s][(ql + r) * OSTR + 16 * n4 + cl] = oacc[n4][r];
        if (cl == 0)
            #pragma unroll
            for (int r = 0; r < 4; ++r)
                mlbuf[s][ql + r] = make_float2(m[r], l[r]);
    }
    __syncthreads();
    if (g == 0) {
        #pragma unroll
        for (int r = 0; r < 4; ++r) {
            const float2 ml1 = mlbuf[s][ql + r];
            const float M  = fmaxf(m[r], ml1.x);
            const float a0 = __builtin_amdgcn_exp2f((m[r]  - M) * LOG2E);
            const float a1 = __builtin_amdgcn_exp2f((ml1.x - M) * LOG2E);
            const float L  = l[r] * a0 + ml1.y * a1;
            const float inv = 1.0f / L;
            const size_t row = (size_t)(b * 4096 + q0 + 16 * s + ql + r) * 64;
            #pragma unroll
            for (int n4 = 0; n4 < 4; ++n4) {
                const float o1 = Om[s][(ql + r) * OSTR + 16 * n4 + cl];
                out[row + 16 * n4 + cl] = (oacc[n4][r] * a0 + o1 * a1) * inv;
            }
        }
    }
}

extern "C" void kernel_launch(void* const* d_in, const int* in_sizes, int n_in,
                              void* d_out, int out_size, void* d_ws, size_t ws_size,
                              hipStream_t stream) {
    const float* qkv = (const float*)d_in[0];
    float* out = (float*)d_out;
    dim3 grid(64, 4);
    dim3 block(512);
    hipLaunchKernelGGL(swa_mfma2, grid, block, 0, stream, qkv, out);
}